// Round 6
// baseline (499.741 us; speedup 1.0000x reference)
//
#include <hip/hip_runtime.h>
#include <hip/hip_bf16.h>
#include <math.h>

#define B_ 4
#define S_ 2048
#define D_ 2048
#define NH_ 16
#define NKV_ 4
#define HD_ 128

typedef short bf16x8 __attribute__((ext_vector_type(8)));
typedef float f32x4 __attribute__((ext_vector_type(4)));
typedef unsigned u32x4 __attribute__((ext_vector_type(4)));
typedef __hip_bfloat16 bf16;

// async 16B/lane global->LDS: lds dest = uniform base + lane*16
#define ASYNC_CP16(gp, lp)                                                    \
  __builtin_amdgcn_global_load_lds(                                           \
      (const __attribute__((address_space(1))) unsigned int*)(gp),            \
      (__attribute__((address_space(3))) unsigned int*)(lp), 16, 0, 0)

__device__ __forceinline__ short f2b(float f) {
  union { bf16 h; short s; } u;
  u.h = __float2bfloat16(f);
  return u.s;
}

// ---------------- f32 -> bf16 conversion (4 elems/thread) ----------------
__global__ __launch_bounds__(256) void cvt_kernel(const float* __restrict__ in,
                                                  bf16* __restrict__ out, int n4) {
  int i = blockIdx.x * 256 + threadIdx.x;
  if (i >= n4) return;
  float4 v = ((const float4*)in)[i];
  union { ushort4 u; bf16 h[4]; } o;
  o.h[0] = __float2bfloat16(v.x);
  o.h[1] = __float2bfloat16(v.y);
  o.h[2] = __float2bfloat16(v.z);
  o.h[3] = __float2bfloat16(v.w);
  ((ushort4*)out)[i] = o.u;
}

// ---------------- fused QKV GEMM + RoPE/transpose epilogue ----------------
// C[8192,3072] = x @ W^T. 128x128 tile, BK=64, 64x64 wave tiles (m97 core).
// hblk 0..15 -> Q head (rope+scale), 16..19 -> K head (rope),
// 20..23 -> V head written TRANSPOSED to vt[B,kv,HD,S].
__global__ __launch_bounds__(256) void gemm_qkv(
    const bf16* __restrict__ A, const bf16* __restrict__ W,
    bf16* __restrict__ qr, bf16* __restrict__ kr, bf16* __restrict__ vt,
    const float* __restrict__ cosp, const float* __restrict__ sinp,
    float qscale) {
  __shared__ __align__(16) bf16 As[128 * 64];
  __shared__ __align__(16) bf16 Bs[128 * 64];
  const int tid = threadIdx.x;
  const int lane = tid & 63, wave = tid >> 6;
  const int wm = (wave & 1) * 64, wn = (wave >> 1) * 64;
  const int m0 = blockIdx.x * 128;
  const int hblk = blockIdx.y;
  const int n0 = hblk * 128;
  const int quad = lane >> 4, c = lane & 15;
  const int K = 2048;

  f32x4 acc[4][4] = {};

  const int sr = lane >> 3;          // row within 8-row group
  const int sg = lane & 7;           // lds slot within row
  const int gc = (sg ^ sr) * 8;      // swizzled global col group
  const bf16* Ap = A + (size_t)(m0 + wave * 32 + sr) * K + gc;
  const bf16* Bp = W + (size_t)(n0 + wave * 32 + sr) * K + gc;

  for (int kb = 0; kb < K; kb += 64) {
    __syncthreads();
#pragma unroll
    for (int i = 0; i < 4; i++) {
      ASYNC_CP16(Ap + (size_t)(i * 8) * K + kb, &As[(wave * 32 + i * 8) * 64]);
      ASYNC_CP16(Bp + (size_t)(i * 8) * K + kb, &Bs[(wave * 32 + i * 8) * 64]);
    }
    __syncthreads();
#pragma unroll
    for (int kk = 0; kk < 2; kk++) {
      const int slot = ((kk * 4 + quad) ^ (c & 7)) * 8;
      bf16x8 af[4], bfr[4];
#pragma unroll
      for (int t = 0; t < 4; t++) {
        af[t]  = *(const bf16x8*)(&As[(wm + t * 16 + c) * 64 + slot]);
        bfr[t] = *(const bf16x8*)(&Bs[(wn + t * 16 + c) * 64 + slot]);
      }
#pragma unroll
      for (int mt = 0; mt < 4; mt++)
#pragma unroll
        for (int nt = 0; nt < 4; nt++)
          acc[mt][nt] = __builtin_amdgcn_mfma_f32_16x16x32_bf16(
              af[mt], bfr[nt], acc[mt][nt], 0, 0, 0);
    }
  }

  if (hblk >= 20) {
    // V: write transposed directly to vt[B, kv, HD, S]; acc regs are 4
    // consecutive s rows -> one short4 (8B) store per (mt, nt).
    const int kv = hblk - 20;
#pragma unroll
    for (int mt = 0; mt < 4; mt++) {
      const int m = m0 + wm + mt * 16 + quad * 4;   // 4 consecutive s from here
      const int b = m >> 11, s0 = m & 2047;
      bf16* obase = vt + ((size_t)(b * NKV_ + kv) * HD_) * S_ + s0;
#pragma unroll
      for (int nt = 0; nt < 4; nt++) {
        const int hd = wn + nt * 16 + c;
        short4 pk;
        pk.x = f2b(acc[mt][nt][0]);
        pk.y = f2b(acc[mt][nt][1]);
        pk.z = f2b(acc[mt][nt][2]);
        pk.w = f2b(acc[mt][nt][3]);
        *(short4*)(obase + (size_t)hd * S_) = pk;
      }
    }
  } else {
    // RoPE: waves 2,3 (cols 64..127) dump f32 to scratch; waves 0,1 combine.
    float* Sc = (float*)As;  // 128 rows x 64 cols f32 = 32 KB (As+Bs)
    __syncthreads();
    if (wave >= 2) {
#pragma unroll
      for (int mt = 0; mt < 4; mt++)
#pragma unroll
        for (int reg = 0; reg < 4; reg++) {
          int lr = wm + mt * 16 + quad * 4 + reg;
#pragma unroll
          for (int nt = 0; nt < 4; nt++)
            Sc[lr * 64 + nt * 16 + c] = acc[mt][nt][reg];
        }
    }
    __syncthreads();
    if (wave < 2) {
      const float scale = (hblk < 16) ? qscale : 1.0f;
#pragma unroll
      for (int mt = 0; mt < 4; mt++)
#pragma unroll
        for (int reg = 0; reg < 4; reg++) {
          int lr = wm + mt * 16 + quad * 4 + reg;
          int m = m0 + lr;
          int b = m >> 11, s = m & 2047;
          const float* cr = cosp + s * HD_;
          const float* sn = sinp + s * HD_;
          bf16* orow = (hblk < 16)
              ? qr + ((size_t)(b * NH_ + hblk) * S_ + s) * HD_
              : kr + ((size_t)(b * NKV_ + (hblk - 16)) * S_ + s) * HD_;
#pragma unroll
          for (int nt = 0; nt < 4; nt++) {
            int d1 = nt * 16 + c, d2 = d1 + 64;
            float q1 = acc[mt][nt][reg];
            float q2 = Sc[lr * 64 + d1];
            float o1 = (q1 * cr[d1] - q2 * sn[d1]) * scale;
            float o2 = (q2 * cr[d2] + q1 * sn[d2]) * scale;
            orow[d1] = __float2bfloat16(o1);
            orow[d2] = __float2bfloat16(o2);
          }
        }
    }
  }
}

// ---------------- Flash attention, 8-wave blocks, paired causal tiles ------
// S^T = K*Q^T so each lane owns ONE q (q = lane&15): in-lane softmax.
__device__ __forceinline__ void attn_step(
    const bf16* __restrict__ Ks, const bf16* __restrict__ Vs,
    bf16* __restrict__ Psw, const bf16x8* qf, f32x4* o,
    float& m_i, float& l_i, bool diag, int kb, int qbase, int quad, int c) {
  f32x4 sacc[4] = {};
#pragma unroll
  for (int kt = 0; kt < 4; kt++) {
    const int slot = ((kt * 4 + quad) ^ (c & 7)) * 8;
#pragma unroll
    for (int mt = 0; mt < 4; mt++) {
      bf16x8 kf = *(const bf16x8*)(&Ks[(mt * 16 + c) * 128 + slot]);
      sacc[mt] = __builtin_amdgcn_mfma_f32_16x16x32_bf16(kf, qf[kt], sacc[mt], 0, 0, 0);
    }
  }
  if (diag) {
    const int qg = qbase + c;
#pragma unroll
    for (int mt = 0; mt < 4; mt++)
#pragma unroll
      for (int r = 0; r < 4; r++)
        if (kb + mt * 16 + quad * 4 + r > qg) sacc[mt][r] = -INFINITY;
  }
  f32x4 mx4 = __builtin_elementwise_max(
      __builtin_elementwise_max(sacc[0], sacc[1]),
      __builtin_elementwise_max(sacc[2], sacc[3]));
  float mx = fmaxf(fmaxf(mx4[0], mx4[1]), fmaxf(mx4[2], mx4[3]));
  mx = fmaxf(mx, __shfl_xor(mx, 16, 64));
  mx = fmaxf(mx, __shfl_xor(mx, 32, 64));
  const float mnew = fmaxf(m_i, mx);
  const float alpha = exp2f(m_i - mnew);
  m_i = mnew;
  const f32x4 mn4 = {mnew, mnew, mnew, mnew};
  f32x4 rs4 = {0.f, 0.f, 0.f, 0.f};
#pragma unroll
  for (int mt = 0; mt < 4; mt++) {
    f32x4 e = sacc[mt] - mn4;
    f32x4 p;
    p[0] = exp2f(e[0]); p[1] = exp2f(e[1]);
    p[2] = exp2f(e[2]); p[3] = exp2f(e[3]);
    rs4 += p;
    u32x4 u = __builtin_bit_cast(u32x4, p) + 0x8000u;
    uint2 pk;
    pk.x = __builtin_amdgcn_perm(u[1], u[0], 0x07060302u);
    pk.y = __builtin_amdgcn_perm(u[3], u[2], 0x07060302u);
    const int pslot = mt * 2 + (quad >> 1);
    *(uint2*)(&Psw[c * 64 + ((pslot ^ (c & 7)) << 3) + (quad & 1) * 4]) = pk;
  }
  float rs = (rs4[0] + rs4[1]) + (rs4[2] + rs4[3]);
  rs += __shfl_xor(rs, 16, 64);
  rs += __shfl_xor(rs, 32, 64);
  l_i = l_i * alpha + rs;
  if (__any(alpha != 1.0f)) {
    f32x4 av;
    av[0] = __shfl(alpha, quad * 4 + 0, 64);
    av[1] = __shfl(alpha, quad * 4 + 1, 64);
    av[2] = __shfl(alpha, quad * 4 + 2, 64);
    av[3] = __shfl(alpha, quad * 4 + 3, 64);
#pragma unroll
    for (int nt = 0; nt < 8; nt++) o[nt] *= av;
  }
#pragma unroll
  for (int kk = 0; kk < 2; kk++) {
    bf16x8 pf = *(const bf16x8*)(&Psw[c * 64 + (((kk * 4 + quad) ^ (c & 7)) << 3)]);
    const int slot = ((kk * 4 + quad) ^ (c & 7)) * 8;
#pragma unroll
    for (int nt = 0; nt < 8; nt++) {
      bf16x8 vf = *(const bf16x8*)(&Vs[(nt * 16 + c) * 64 + slot]);
      o[nt] = __builtin_amdgcn_mfma_f32_16x16x32_bf16(pf, vf, o[nt], 0, 0, 0);
    }
  }
}

// 512 threads = 8 waves; block owns 128 Q rows; pairing j <-> 15-j gives
// uniform 34 K-tile steps. LDS 48KB -> 3 blocks/CU (24 waves, 75% cap).
__global__ __launch_bounds__(512, 6) void attn_kernel(const bf16* __restrict__ Q,
                                                      const bf16* __restrict__ Kr,
                                                      const bf16* __restrict__ Vt,
                                                      float* __restrict__ O) {
  __shared__ __align__(16) bf16 Ks[64 * 128];   // 16 KB
  __shared__ __align__(16) bf16 Vs[128 * 64];   // 16 KB
  __shared__ __align__(16) bf16 Ps[8][16 * 64]; // 16 KB (swizzled, no pad)

  const int tid = threadIdx.x, lane = tid & 63, wave = tid >> 6;  // wave 0..7
  const int quad = lane >> 4, c = lane & 15;
  const int j = blockIdx.x;                 // pair index 0..7
  const int bh = blockIdx.y;
  const int b = bh >> 4, h = bh & 15, kv = h >> 2;
  bf16* Psw = &Ps[wave][0];

  const bf16* kbase = Kr + (size_t)(b * NKV_ + kv) * S_ * HD_;
  const bf16* vbase = Vt + (size_t)(b * NKV_ + kv) * HD_ * S_;

  // staging: 512 thr x 16B x 2 insts = 16KB per buffer per step
  int koff[2], voff[2];
  {
    const int kl = lane >> 4;       // 4 rows per K inst (128 cols)
    const int ks = lane & 15;
#pragma unroll
    for (int i = 0; i < 2; i++) {
      int r = wave * 8 + i * 4 + kl;
      koff[i] = r * HD_ + ((ks ^ (r & 7)) * 8);
    }
    const int vl = lane >> 3;       // 8 rows per V inst (64 cols)
    const int vs = lane & 7;
#pragma unroll
    for (int i = 0; i < 2; i++) {
      int r = wave * 16 + i * 8 + vl;
      voff[i] = r * S_ + ((vs ^ (vl & 7)) * 8);
    }
  }

#pragma unroll 1
  for (int pass = 0; pass < 2; ++pass) {
    const int qt = pass ? (15 - j) : j;
    const int q0 = qt * 128;
    const int qb = q0 + wave * 16;

    bf16x8 qf[4];
    {
      const bf16* qp = Q + ((size_t)(b * NH_ + h) * S_ + qb + c) * HD_;
#pragma unroll
      for (int kt = 0; kt < 4; kt++)
        qf[kt] = *(const bf16x8*)(qp + kt * 32 + quad * 8);
    }
    f32x4 o_acc[8] = {};
    float m_i = -INFINITY, l_i = 0.f;

    const int nsteps = 2 * qt + 2;
#pragma unroll 1
    for (int it = 0; it < nsteps; ++it) {
      const int kb = it * 64;
      __syncthreads();
#pragma unroll
      for (int i = 0; i < 2; i++) {
        ASYNC_CP16(kbase + (size_t)kb * HD_ + koff[i], &Ks[(wave * 8 + i * 4) * 128]);
        ASYNC_CP16(vbase + kb + voff[i], &Vs[(wave * 16 + i * 8) * 64]);
      }
      __syncthreads();
      attn_step(Ks, Vs, Psw, qf, o_acc, m_i, l_i, kb + 63 > qb, kb, qb, quad, c);
    }

    // epilogue
    float inv[4];
#pragma unroll
    for (int r = 0; r < 4; r++) inv[r] = 1.0f / __shfl(l_i, quad * 4 + r, 64);
    float* obase = O + (size_t)b * S_ * D_ + (size_t)h * HD_;
#pragma unroll
    for (int nt = 0; nt < 8; nt++)
#pragma unroll
      for (int r = 0; r < 4; r++)
        obase[(size_t)(qb + quad * 4 + r) * D_ + nt * 16 + c] = o_acc[nt][r] * inv[r];
  }
}

// ---------------- host launch ----------------
extern "C" void kernel_launch(void* const* d_in, const int* in_sizes, int n_in,
                              void* d_out, int out_size, void* d_ws, size_t ws_size,
                              hipStream_t stream) {
  const float* x    = (const float*)d_in[0];
  const float* cosp = (const float*)d_in[1];
  const float* sinp = (const float*)d_in[2];
  const float* wq   = (const float*)d_in[3];
  const float* wk   = (const float*)d_in[4];
  const float* wv   = (const float*)d_in[5];
  float* out = (float*)d_out;

  char* ws = (char*)d_ws;
  const size_t MB = 1024 * 1024;
  bf16* xb    = (bf16*)(ws + 0);         // 32MB
  bf16* wqkvb = (bf16*)(ws + 32 * MB);   // 12MB: [3072, 2048] concat
  bf16* qr    = (bf16*)(ws + 44 * MB);   // 32MB
  bf16* kr    = (bf16*)(ws + 76 * MB);   // 8MB
  bf16* vt    = (bf16*)(ws + 84 * MB);   // 8MB

  cvt_kernel<<<16384, 256, 0, stream>>>(x, xb, 4194304);
  cvt_kernel<<<4096, 256, 0, stream>>>(wq, wqkvb, 1048576);
  cvt_kernel<<<1024, 256, 0, stream>>>(wk, wqkvb + 4194304, 262144);
  cvt_kernel<<<1024, 256, 0, stream>>>(wv, wqkvb + 5242880, 262144);

  const float qscale = 1.4426950408889634f / 11.313708498984761f;
  gemm_qkv<<<dim3(64, 24), 256, 0, stream>>>(xb, wqkvb, qr, kr, vt,
                                             cosp, sinp, qscale);

  attn_kernel<<<dim3(8, 64), 512, 0, stream>>>(qr, kr, vt, out);
}